// Round 15
// baseline (330.412 us; speedup 1.0000x reference)
//
#include <hip/hip_runtime.h>
#include <math.h>

#define B_ 4
#define T_ 4096
#define D_ 1024
#define K_ 8
#define M_ 12          // candidates kept per row/segment (refined to top-K)

// f16 MFMA path: block = 256j x 128i (8 waves), SEGJT=1, NSEG=16 segment slots
#define NSEG_F16 16
#define NTILE_B  272   // sum over t=0..31 (128-row tiles) of ((t>>1)+1)

// fallback fp32-path tile params
#define BI 32
#define BJ 128
#define DC 32

typedef __attribute__((ext_vector_type(8))) _Float16 f16x8;
typedef __attribute__((ext_vector_type(16))) float f32x16;

// branch-free sorted insert into ascending top-12 (tv[0]=min). Static indices.
__device__ __forceinline__ void ins12(float (&tv)[M_], int (&tix)[M_], float v, int nj) {
#pragma unroll
    for (int k = 0; k < M_; ++k) {
        const float nxt = (k < M_ - 1) ? tv[k + 1] : INFINITY;
        const int   nxi = (k < M_ - 1) ? tix[k + 1] : -1;
        const bool  up  = v > nxt;
        const bool  mid = v > tv[k];
        tv[k]  = up ? nxt : (mid ? v  : tv[k]);
        tix[k] = up ? nxi : (mid ? nj : tix[k]);
    }
}

// ---------------- Kernel 1 (fused): row norms (fp64 truth) + normalize + pack-major transpose ----------------
__global__ __launch_bounds__(256) void norm_transpose_kernel(const float* __restrict__ x,
                                                             float* __restrict__ rn32,
                                                             double* __restrict__ rn64,
                                                             _Float16* __restrict__ xf) {
    const int blk = blockIdx.x;                  // 0 .. B*T/64-1
    const int b   = blk >> 6;                    // 64 blocks per batch
    const int i0b = (blk & 63) << 6;
    const int tid = threadIdx.x;
    const int r   = tid >> 2;                    // 0..63 row within tile
    const int q   = tid & 3;                     // quarter
    const int row = i0b + r;
    const float* src = x + ((size_t)(b << 12) + row) * D_ + (q << 8);   // 256 floats

    double ss = 0.0;
#pragma unroll 8
    for (int g = 0; g < 64; ++g) {
        const float4 v = reinterpret_cast<const float4*>(src)[g];
        ss += (double)v.x * v.x + (double)v.y * v.y +
              (double)v.z * v.z + (double)v.w * v.w;
    }
    ss += __shfl_xor(ss, 1);
    ss += __shfl_xor(ss, 2);
    const double rn = 1.0 / (sqrt(ss) + 1e-8);
    if (q == 0) {
        rn64[(b << 12) + row] = rn;
        rn32[(b << 12) + row] = (float)rn;
    }
    const float rnf = (float)rn;
    f16x8* dst = reinterpret_cast<f16x8*>(xf) + (size_t)b * 128 * T_;
#pragma unroll
    for (int g = 0; g < 32; ++g) {
        const int p = (q << 5) + g;              // packs 32q .. 32q+31
        const float4 a = reinterpret_cast<const float4*>(src)[g << 1];
        const float4 c = reinterpret_cast<const float4*>(src)[(g << 1) + 1];
        f16x8 h;
        h[0] = (_Float16)(a.x * rnf); h[1] = (_Float16)(a.y * rnf);
        h[2] = (_Float16)(a.z * rnf); h[3] = (_Float16)(a.w * rnf);
        h[4] = (_Float16)(c.x * rnf); h[5] = (_Float16)(c.y * rnf);
        h[6] = (_Float16)(c.z * rnf); h[7] = (_Float16)(c.w * rnf);
        dst[(size_t)p * T_ + row] = h;
    }
}

// ---------------- Kernel 1-fallback: row norms only (fp32 path) ----------------
__global__ __launch_bounds__(256) void norm_kernel(const float* __restrict__ x,
                                                   float* __restrict__ rn32,
                                                   double* __restrict__ rn64) {
    const int row = blockIdx.x;
    const int tid = threadIdx.x;
    const float4 v = reinterpret_cast<const float4*>(x + (size_t)row * D_)[tid];
    double ss = (double)v.x * v.x + (double)v.y * v.y +
                (double)v.z * v.z + (double)v.w * v.w;
    for (int o = 32; o > 0; o >>= 1) ss += __shfl_down(ss, o);
    __shared__ double ws[4];
    if ((tid & 63) == 0) ws[tid >> 6] = ss;
    __syncthreads();
    if (tid == 0) {
        double s = ws[0] + ws[1] + ws[2] + ws[3];
        double rn = 1.0 / (sqrt(s) + 1e-8);
        rn64[row] = rn;
        rn32[row] = (float)rn;
    }
}

// ---------------- Kernel 2a: fp16 MFMA similarity — 8-wave 256j x 128i tiles ----------------
// Grid: B * 272; block u -> (t, s), t = 128-row tile (0..31), s < (t>>1)+1; groups
// q=t>>1 have 2 tiles x (q+1) segments, offset C(q)=q(q+1). Uniform work per block.
// Block: 512 thr = 8 waves: wj = wid&3 (j slice 64), wi = wid>>2 (i slice 64).
// Per-wave body IDENTICAL to r13 (2 cold j-loads + 2 L1-hot i-loads -> 4 MFMA, 4 accs);
// L1 dedups shared frags across waves -> unique traffic/block 768KB vs r13's 2x640KB.
__global__ __launch_bounds__(512, 4) void simtopk_f16(const _Float16* __restrict__ xf,
                                                      int* __restrict__ cand_idx,
                                                      float* __restrict__ cand_val) {
    __shared__ float mv[128 * 4 * M_];           // 24KB merge buffers
    __shared__ int   mi[128 * 4 * M_];           // 24KB

    const int bid = blockIdx.x;
    const int b   = bid / NTILE_B;
    const int u   = bid - b * NTILE_B;
    int q = 0;
#pragma unroll
    for (int qq = 1; qq < 16; ++qq) if (u >= qq * (qq + 1)) q = qq;
    const int rr = u - q * (q + 1);
    const int dt = rr / (q + 1);
    const int s  = rr - dt * (q + 1);
    const int t  = (q << 1) + dt;                // 0..31
    const int i0 = t << 7;
    const int j0 = s << 8;

    const int tid  = threadIdx.x;
    const int wid  = tid >> 6;                   // 0..7
    const int wj   = wid & 3;
    const int wi   = wid >> 2;
    const int lane = tid & 63;
    const int l31  = lane & 31;
    const int lhi  = lane >> 5;

    const f16x8* Fb = reinterpret_cast<const f16x8*>(xf) + (size_t)b * 128 * T_;

    const int ib  = i0 + (wi << 6);              // this wave's 64-i slice base
    const int myc = ib + (lhi << 5) + l31;       // the single i column this lane owns
    const int jbw = j0 + (wj << 6);              // this wave's 64-j slice base

    float tv[M_]; int tix[M_];
#pragma unroll
    for (int k = 0; k < M_; ++k) { tv[k] = -INFINITY; tix[k] = -1; }

    f32x16 acc00, acc01, acc10, acc11;
#pragma unroll
    for (int r = 0; r < 16; ++r) { acc00[r] = 0.f; acc01[r] = 0.f; acc10[r] = 0.f; acc11[r] = 0.f; }

#pragma unroll 4
    for (int kh = 0; kh < 16; ++kh) {            // K chunks of 64 elements = 8 packs
#pragma unroll
        for (int ks = 0; ks < 4; ++ks) {
            const int p = (kh << 3) + (ks << 1) + lhi;
            const f16x8* Fp = Fb + (size_t)p * T_;
            const f16x8 aj0 = Fp[jbw + l31];
            const f16x8 aj1 = Fp[jbw + 32 + l31];
            const f16x8 bi0 = Fp[ib + l31];
            const f16x8 bi1 = Fp[ib + 32 + l31];
            acc00 = __builtin_amdgcn_mfma_f32_32x32x16_f16(aj0, bi0, acc00, 0, 0, 0);
            acc01 = __builtin_amdgcn_mfma_f32_32x32x16_f16(aj0, bi1, acc01, 0, 0, 0);
            acc10 = __builtin_amdgcn_mfma_f32_32x32x16_f16(aj1, bi0, acc10, 0, 0, 0);
            acc11 = __builtin_amdgcn_mfma_f32_32x32x16_f16(aj1, bi1, acc11, 0, 0, 0);
        }
    }

    // consolidate to one column per lane and scan 64 j-values in registers
#pragma unroll
    for (int r = 0; r < 16; ++r) {
        const float swA = __shfl_xor(acc00[r], 32);
        const float swB = __shfl_xor(acc01[r], 32);
        const float swC = __shfl_xor(acc10[r], 32);
        const float swD = __shfl_xor(acc11[r], 32);
        const int rbase = (r & 3) + ((r >> 2) << 3);
        const int rown  = jbw + rbase + (lhi << 2);        // own half rows
        const int rotn  = jbw + rbase + ((1 - lhi) << 2);  // partner half rows
        const float va = lhi ? acc01[r] : acc00[r];        // (rown,      myc)
        const float vb = lhi ? swB      : swA;             // (rotn,      myc)
        const float vc = lhi ? acc11[r] : acc10[r];        // (rown + 32, myc)
        const float vd = lhi ? swD      : swC;             // (rotn + 32, myc)
        if (rown <= myc      && va > tv[0]) ins12(tv, tix, va, rown);
        if (rotn <= myc      && vb > tv[0]) ins12(tv, tix, vb, rotn);
        if (rown + 32 <= myc && vc > tv[0]) ins12(tv, tix, vc, rown + 32);
        if (rotn + 32 <= myc && vd > tv[0]) ins12(tv, tix, vd, rotn + 32);
    }

    // merge: 4 wj-lists per column (128 columns) via LDS
    const int coll = (wi << 6) + (lhi << 5) + l31;          // 0..127
#pragma unroll
    for (int k = 0; k < M_; ++k) {
        mv[(coll * 4 + wj) * M_ + k] = tv[k];
        mi[(coll * 4 + wj) * M_ + k] = tix[k];
    }
    __syncthreads();
    if (tid < 128) {
        float gv[M_]; int gx[M_];
#pragma unroll
        for (int k = 0; k < M_; ++k) { gv[k] = -INFINITY; gx[k] = -1; }
        for (int ls = 0; ls < 4; ++ls) {
            const int base = (tid * 4 + ls) * M_;
            for (int k = M_ - 1; k >= 0; --k) {      // stored ascending; walk descending
                const float v = mv[base + k];
                if (!(v > gv[0])) break;
                const int nj = mi[base + k];
                if (nj >= 0) ins12(gv, gx, v, nj);
            }
        }
        const size_t cb = ((size_t)(b * T_ + i0 + tid) * NSEG_F16 + s) * M_;
#pragma unroll
        for (int k = 0; k < M_; ++k) {
            cand_val[cb + k] = gv[M_ - 1 - k];
            cand_idx[cb + k] = gx[M_ - 1 - k];
        }
    }
}

// ---------------- Kernel 2b: fp32 fallback (used only if workspace too small) ----------------
__global__ __launch_bounds__(256) void simtopk_fp32(const float* __restrict__ x,
                                                    const float* __restrict__ rn32,
                                                    int* __restrict__ cand_idx,
                                                    float* __restrict__ cand_val,
                                                    int SEGJT, int NSEGMAX) {
    __shared__ __align__(16) float smem2[DC * 36 + DC * 132];
    float (*At)[36]  = reinterpret_cast<float(*)[36]>(smem2);
    float (*Bt)[132] = reinterpret_cast<float(*)[132]>(smem2 + DC * 36);
    float (*Cs)[132] = reinterpret_cast<float(*)[132]>(smem2);

    const int bid = blockIdx.x;
    const int s   = bid % NSEGMAX;
    const int bt  = bid / NSEGMAX;
    const int t   = bt & 127;
    const int b   = bt >> 7;
    const int njt = (t >> 2) + 1;
    const int jt0 = s * SEGJT;
    if (jt0 >= njt) return;
    const int jt1 = min(jt0 + SEGJT, njt);
    const int i0  = t * BI;

    const int tid = threadIdx.x;
    const int tx  = tid & 31;
    const int ty  = tid >> 5;
    const float* xb = x + (size_t)b * T_ * D_;
    const float* rb = rn32 + b * T_;

    const int ai  = tid >> 3;
    const int adq = (tid & 7) << 2;

    float tv[M_]; int tix[M_];
#pragma unroll
    for (int k = 0; k < M_; ++k) { tv[k] = -INFINITY; tix[k] = -1; }

    for (int jt = jt0; jt < jt1; ++jt) {
        const int j0 = jt << 7;
        float acc[4][4];
#pragma unroll
        for (int ii = 0; ii < 4; ++ii)
#pragma unroll
            for (int jj = 0; jj < 4; ++jj) acc[ii][jj] = 0.f;

        for (int dc = 0; dc < D_; dc += DC) {
            __syncthreads();
            {
                const float rn = rb[i0 + ai];
                float4 v = *reinterpret_cast<const float4*>(&xb[(size_t)(i0 + ai) * D_ + dc + adq]);
                At[adq + 0][ai] = v.x * rn;
                At[adq + 1][ai] = v.y * rn;
                At[adq + 2][ai] = v.z * rn;
                At[adq + 3][ai] = v.w * rn;
            }
#pragma unroll
            for (int l = 0; l < 4; ++l) {
                const int li = tid + (l << 8);
                const int j  = li >> 3;
                const int dq = (li & 7) << 2;
                const float rn = rb[j0 + j];
                float4 v = *reinterpret_cast<const float4*>(&xb[(size_t)(j0 + j) * D_ + dc + dq]);
                Bt[dq + 0][j] = v.x * rn;
                Bt[dq + 1][j] = v.y * rn;
                Bt[dq + 2][j] = v.z * rn;
                Bt[dq + 3][j] = v.w * rn;
            }
            __syncthreads();
#pragma unroll 8
            for (int d = 0; d < DC; ++d) {
                float4 a  = *reinterpret_cast<const float4*>(&At[d][ty << 2]);
                float4 bv = *reinterpret_cast<const float4*>(&Bt[d][tx << 2]);
                float av[4] = {a.x, a.y, a.z, a.w};
                float bw[4] = {bv.x, bv.y, bv.z, bv.w};
#pragma unroll
                for (int ii = 0; ii < 4; ++ii)
#pragma unroll
                    for (int jj = 0; jj < 4; ++jj)
                        acc[ii][jj] = fmaf(av[ii], bw[jj], acc[ii][jj]);
            }
        }
        __syncthreads();
#pragma unroll
        for (int ii = 0; ii < 4; ++ii) {
            *reinterpret_cast<float4*>(&Cs[(ty << 2) + ii][tx << 2]) =
                make_float4(acc[ii][0], acc[ii][1], acc[ii][2], acc[ii][3]);
        }
        __syncthreads();
        if (tid < BI) {
            const int gi   = i0 + tid;
            const int jmax = gi - j0;
            const int cend = jmax < BJ - 1 ? jmax : BJ - 1;
            for (int c = 0; c <= cend; ++c) {
                const float v = Cs[tid][c];
                if (v > tv[0]) ins12(tv, tix, v, j0 + c);
            }
        }
    }
    if (tid < BI) {
        const size_t base = ((size_t)(b * T_ + i0 + tid) * NSEGMAX + s) * M_;
#pragma unroll
        for (int k = 0; k < M_; ++k) {
            cand_idx[base + k] = tix[M_ - 1 - k];
            cand_val[base + k] = tv[M_ - 1 - k];
        }
    }
}

// ---------------- Kernel 3a: wave-per-row rank-merge + fp64 refine -> sel[] ----------------
__global__ __launch_bounds__(256) void select_kernel(const float* __restrict__ x,
                                                     const double* __restrict__ rn64,
                                                     const int* __restrict__ cand_idx,
                                                     const float* __restrict__ cand_val,
                                                     int* __restrict__ sel,
                                                     int SEGJT, int NSEGMAX, int SHIFT) {
    const int tid  = threadIdx.x;
    const int wid  = tid >> 6;
    const int lane = tid & 63;
    const int row  = (blockIdx.x << 2) + wid;
    const int b    = row >> 12;
    const int i    = row & (T_ - 1);
    const int njt  = (i >> SHIFT) + 1;
    const int nseg = (njt + SEGJT - 1) / SEGJT;
    const int ncand = nseg * M_;              // <= 192

    __shared__ unsigned long long keys[4][192];
    __shared__ float v12[4][12];
    __shared__ int   i12[4][12];

    if (lane < 12) { v12[wid][lane] = -INFINITY; i12[wid][lane] = -1; }

    const size_t cb = (size_t)row * NSEGMAX * M_;
    float cv[3]; int cj[3]; unsigned long long kk[3];
#pragma unroll
    for (int q = 0; q < 3; ++q) {
        const int c = lane + (q << 6);
        if (c < ncand) { cv[q] = cand_val[cb + c]; cj[q] = cand_idx[cb + c]; }
        else           { cv[q] = -INFINITY;        cj[q] = -1; }
        unsigned u = __float_as_uint(cv[q]);
        unsigned so = (u & 0x80000000u) ? ~u : (u | 0x80000000u);
        kk[q] = (cj[q] >= 0)
              ? ((((unsigned long long)so) << 32) | (unsigned long long)(0xFFFFFFFFu - (unsigned)cj[q]))
              : 0ull;
        keys[wid][lane + (q << 6)] = kk[q];
    }
    int nv = 0;
#pragma unroll
    for (int q = 0; q < 3; ++q) nv += __popcll(__ballot(cj[q] >= 0));
    __syncthreads();

    int rk0 = 0, rk1 = 0, rk2 = 0;
#pragma unroll 4
    for (int c = 0; c < ncand; ++c) {
        const unsigned long long kc = keys[wid][c];
        rk0 += (kc > kk[0]);
        rk1 += (kc > kk[1]);
        rk2 += (kc > kk[2]);
    }
    if (cj[0] >= 0 && rk0 < 12) { v12[wid][rk0] = cv[0]; i12[wid][rk0] = cj[0]; }
    if (cj[1] >= 0 && rk1 < 12) { v12[wid][rk1] = cv[1]; i12[wid][rk1] = cj[1]; }
    if (cj[2] >= 0 && rk2 < 12) { v12[wid][rk2] = cv[2]; i12[wid][rk2] = cj[2]; }
    __syncthreads();

    const float v8 = v12[wid][7];
    const float v9 = v12[wid][8];
    const bool refine = (nv > K_) && (v8 - v9 < 2e-4f);   // wave-uniform

    int outj = -1;
    int cnt;
    if (refine) {
        const float* xi = x + (size_t)row * D_;
        float4 xa[4];
#pragma unroll
        for (int q = 0; q < 4; ++q)
            xa[q] = *reinterpret_cast<const float4*>(xi + (lane << 4) + (q << 2));
        double sim[12]; int jj[12];
#pragma unroll
        for (int c = 0; c < 12; ++c) {
            const int j = i12[wid][c];
            jj[c] = j;
            double s = 0.0;
            if (j >= 0) {
                const float* xj = x + ((size_t)(b << 12) + j) * D_;
#pragma unroll
                for (int q = 0; q < 4; ++q) {
                    const float4 xc = *reinterpret_cast<const float4*>(xj + (lane << 4) + (q << 2));
                    s += (double)xa[q].x * xc.x + (double)xa[q].y * xc.y +
                         (double)xa[q].z * xc.z + (double)xa[q].w * xc.w;
                }
            }
            sim[c] = s;
        }
#pragma unroll
        for (int c = 0; c < 12; ++c) {
#pragma unroll
            for (int o = 1; o < 64; o <<= 1) sim[c] += __shfl_xor(sim[c], o);
        }
        const double rni = rn64[row];
#pragma unroll
        for (int c = 0; c < 12; ++c)
            sim[c] = (jj[c] >= 0) ? sim[c] * rni * rn64[(b << 12) + jj[c]] : -1e300;
        unsigned msel = 0;
#pragma unroll
        for (int c = 0; c < 12; ++c) {
            int r = 0;
#pragma unroll
            for (int d = 0; d < 12; ++d) {
                if (d == c) continue;
                r += (sim[d] > sim[c]) || (sim[d] == sim[c] && jj[d] < jj[c]);
            }
            if (jj[c] >= 0 && r < 8) msel |= (1u << c);
        }
        cnt = __popc(msel); if (cnt < 1) cnt = 1;
        if (lane < 8) {
            int seen = 0;
#pragma unroll
            for (int c = 0; c < 12; ++c) {
                if (msel & (1u << c)) { if (seen == lane) outj = jj[c]; ++seen; }
            }
        }
    } else {
        cnt = nv < K_ ? nv : K_; if (cnt < 1) cnt = 1;
        if (lane < 8) outj = i12[wid][lane];
    }
    if (lane < 8) sel[(row << 4) + lane] = outj;
    if (lane == 8) sel[(row << 4) + 8] = cnt;
}

// ---------------- Kernel 3b: streaming gather + gate epilogue ----------------
__global__ __launch_bounds__(256) void gather_kernel(const float* __restrict__ x,
                                                     const int* __restrict__ sel,
                                                     const float* __restrict__ gain,
                                                     const float* __restrict__ bias,
                                                     const float* __restrict__ lmix,
                                                     const float* __restrict__ lscale,
                                                     float* __restrict__ out) {
    const int row = blockIdx.x;
    const int b   = row >> 12;
    const int tid = threadIdx.x;
    const int sb  = row << 4;

    int js[8];
#pragma unroll
    for (int k = 0; k < 8; ++k) js[k] = sel[sb + k];
    const int cnt = sel[sb + 8];

    const float4 xiv = reinterpret_cast<const float4*>(x + (size_t)row * D_)[tid];
    float mx = 0.f, my = 0.f, mz = 0.f, mw = 0.f;
#pragma unroll
    for (int k = 0; k < 8; ++k) {
        const int j = js[k];
        if (j >= 0) {
            const float4 xc = reinterpret_cast<const float4*>(
                x + ((size_t)(b << 12) + j) * D_)[tid];
            mx += xc.x; my += xc.y; mz += xc.z; mw += xc.w;
        }
    }
    const float inv = 1.0f / (float)cnt;
    const float lm = lmix[0], ls = lscale[0];
    const float mix = 1.0f / (1.0f + expf(-lm));
    const float sc  = (fmaxf(ls, 0.f) + log1pf(expf(-fabsf(ls)))) + 0.01f;
    const float4 g  = reinterpret_cast<const float4*>(gain)[tid];
    const float4 bb = reinterpret_cast<const float4*>(bias)[tid];

    float4 o4;
    {
        float m, bl, y;
        m = mx * inv; bl = mix * xiv.x + (1.f - mix) * m; y = bl * g.x + bb.x;
        o4.x = 0.5f * y * (1.f + erff(y * 0.70710678118654752f)) * sc;
        m = my * inv; bl = mix * xiv.y + (1.f - mix) * m; y = bl * g.y + bb.y;
        o4.y = 0.5f * y * (1.f + erff(y * 0.70710678118654752f)) * sc;
        m = mz * inv; bl = mix * xiv.z + (1.f - mix) * m; y = bl * g.z + bb.z;
        o4.z = 0.5f * y * (1.f + erff(y * 0.70710678118654752f)) * sc;
        m = mw * inv; bl = mix * xiv.w + (1.f - mix) * m; y = bl * g.w + bb.w;
        o4.w = 0.5f * y * (1.f + erff(y * 0.70710678118654752f)) * sc;
    }
    reinterpret_cast<float4*>(out + (size_t)row * D_)[tid] = o4;
}

// ---------------- launch ----------------
extern "C" void kernel_launch(void* const* d_in, const int* in_sizes, int n_in,
                              void* d_out, int out_size, void* d_ws, size_t ws_size,
                              hipStream_t stream) {
    const float* x      = (const float*)d_in[0];
    const float* gain   = (const float*)d_in[1];
    const float* bias   = (const float*)d_in[2];
    const float* lmix   = (const float*)d_in[3];
    const float* lscale = (const float*)d_in[4];
    float* out = (float*)d_out;

    char* ws = (char*)d_ws;
    float*  rn32 = (float*)ws;                        // 64 KB
    double* rn64 = (double*)(ws + 65536);             // 128 KB
    int*    selb = (int*)(ws + 196608);               // B*T*16 ints = 1 MB
    const size_t base2 = 196608 + (size_t)B_ * T_ * 16 * 4;
    const size_t HF = (size_t)B_ * T_ * D_ * 2;       // 32 MB fp16 pack-major array
    _Float16* xf = (_Float16*)(ws + base2);
    const size_t base_cand = base2 + HF;

    auto candBytes = [](int nseg) { return (size_t)B_ * T_ * nseg * M_ * 8; };

    const bool use_f16 = (ws_size >= base_cand + candBytes(NSEG_F16));

    if (use_f16) {
        int*   cidx = (int*)(ws + base_cand);
        float* cval = (float*)(ws + base_cand + candBytes(NSEG_F16) / 2);
        norm_transpose_kernel<<<dim3(B_ * T_ / 64), dim3(256), 0, stream>>>(x, rn32, rn64, xf);
        simtopk_f16<<<dim3(B_ * NTILE_B), dim3(512), 0, stream>>>(xf, cidx, cval);
        select_kernel<<<dim3(B_ * T_ / 4), dim3(256), 0, stream>>>(
            x, rn64, cidx, cval, selb, 1, NSEG_F16, 8);
    } else {
        int SEG2, NSEG2;
        if (ws_size >= base2 + candBytes(9)) { SEG2 = 4;  NSEG2 = 9; }
        else                                 { SEG2 = 33; NSEG2 = 1; }
        int*   cidx = (int*)(ws + base2);
        float* cval = (float*)(ws + base2 + candBytes(NSEG2) / 2);
        norm_kernel<<<dim3(B_ * T_), dim3(256), 0, stream>>>(x, rn32, rn64);
        simtopk_fp32<<<dim3(B_ * 128 * NSEG2), dim3(256), 0, stream>>>(x, rn32, cidx, cval, SEG2, NSEG2);
        select_kernel<<<dim3(B_ * T_ / 4), dim3(256), 0, stream>>>(
            x, rn64, cidx, cval, selb, SEG2, NSEG2, 7);
    }
    gather_kernel<<<dim3(B_ * T_), dim3(256), 0, stream>>>(
        x, selb, gain, bias, lmix, lscale, out);
}

// Round 16
// 300.552 us; speedup vs baseline: 1.0994x; 1.0994x over previous
//
#include <hip/hip_runtime.h>
#include <math.h>

#define B_ 4
#define T_ 4096
#define D_ 1024
#define K_ 8
#define M_ 12          // candidates kept per row/segment (refined to top-K)

// f16 MFMA path: SEGJT=1 (one 256-wide j-tile per block), NSEG=16 segment slots
#define NSEG_F16 16
#define NTILE_B  544   // sum over t=0..63 of njt(t) = (t>>2)+1

// fallback fp32-path tile params
#define BI 32
#define BJ 128
#define DC 32

typedef __attribute__((ext_vector_type(8))) _Float16 f16x8;
typedef __attribute__((ext_vector_type(16))) float f32x16;

// branch-free sorted insert into ascending top-12 (tv[0]=min). Static indices.
__device__ __forceinline__ void ins12(float (&tv)[M_], int (&tix)[M_], float v, int nj) {
#pragma unroll
    for (int k = 0; k < M_; ++k) {
        const float nxt = (k < M_ - 1) ? tv[k + 1] : INFINITY;
        const int   nxi = (k < M_ - 1) ? tix[k + 1] : -1;
        const bool  up  = v > nxt;
        const bool  mid = v > tv[k];
        tv[k]  = up ? nxt : (mid ? v  : tv[k]);
        tix[k] = up ? nxi : (mid ? nj : tix[k]);
    }
}

// ---------------- Kernel 1 (fused): row norms (fp64 truth) + normalize + pack-major transpose ----------------
// Block: 64 rows of one batch. Thread (r = tid>>2, q = tid&3) owns row r's quarter q
// (256 floats). Phase 1: fp64 sum-of-squares + quad shfl reduce -> rn. Phase 2: re-read
// quarter (L2-hot), scale, write fp16 packs 32q..32q+31 at xf8[b][p][row].
__global__ __launch_bounds__(256) void norm_transpose_kernel(const float* __restrict__ x,
                                                             float* __restrict__ rn32,
                                                             double* __restrict__ rn64,
                                                             _Float16* __restrict__ xf) {
    const int blk = blockIdx.x;                  // 0 .. B*T/64-1
    const int b   = blk >> 6;                    // 64 blocks per batch
    const int i0b = (blk & 63) << 6;
    const int tid = threadIdx.x;
    const int r   = tid >> 2;                    // 0..63 row within tile
    const int q   = tid & 3;                     // quarter
    const int row = i0b + r;
    const float* src = x + ((size_t)(b << 12) + row) * D_ + (q << 8);   // 256 floats

    double ss = 0.0;
#pragma unroll 8
    for (int g = 0; g < 64; ++g) {
        const float4 v = reinterpret_cast<const float4*>(src)[g];
        ss += (double)v.x * v.x + (double)v.y * v.y +
              (double)v.z * v.z + (double)v.w * v.w;
    }
    // quad reduce (lanes 4r..4r+3 are in the same wave)
    ss += __shfl_xor(ss, 1);
    ss += __shfl_xor(ss, 2);
    const double rn = 1.0 / (sqrt(ss) + 1e-8);
    if (q == 0) {
        rn64[(b << 12) + row] = rn;
        rn32[(b << 12) + row] = (float)rn;
    }
    const float rnf = (float)rn;
    f16x8* dst = reinterpret_cast<f16x8*>(xf) + (size_t)b * 128 * T_;
#pragma unroll
    for (int g = 0; g < 32; ++g) {
        const int p = (q << 5) + g;              // packs 32q .. 32q+31
        const float4 a = reinterpret_cast<const float4*>(src)[g << 1];
        const float4 c = reinterpret_cast<const float4*>(src)[(g << 1) + 1];
        f16x8 h;
        h[0] = (_Float16)(a.x * rnf); h[1] = (_Float16)(a.y * rnf);
        h[2] = (_Float16)(a.z * rnf); h[3] = (_Float16)(a.w * rnf);
        h[4] = (_Float16)(c.x * rnf); h[5] = (_Float16)(c.y * rnf);
        h[6] = (_Float16)(c.z * rnf); h[7] = (_Float16)(c.w * rnf);
        dst[(size_t)p * T_ + row] = h;
    }
}

// ---------------- Kernel 1-fallback: row norms only (fp32 path) ----------------
__global__ __launch_bounds__(256) void norm_kernel(const float* __restrict__ x,
                                                   float* __restrict__ rn32,
                                                   double* __restrict__ rn64) {
    const int row = blockIdx.x;
    const int tid = threadIdx.x;
    const float4 v = reinterpret_cast<const float4*>(x + (size_t)row * D_)[tid];
    double ss = (double)v.x * v.x + (double)v.y * v.y +
                (double)v.z * v.z + (double)v.w * v.w;
    for (int o = 32; o > 0; o >>= 1) ss += __shfl_down(ss, o);
    __shared__ double ws[4];
    if ((tid & 63) == 0) ws[tid >> 6] = ss;
    __syncthreads();
    if (tid == 0) {
        double s = ws[0] + ws[1] + ws[2] + ws[3];
        double rn = 1.0 / (sqrt(s) + 1e-8);
        rn64[row] = rn;
        rn32[row] = (float)rn;
    }
}

// ---------------- Kernel 2a: fp16 MFMA similarity — uniform-work streaming tiles ----------------
// Grid: B * 544 blocks; block u unflattens to (t, s) with s < njt(t) — every block does
// EXACTLY one 256(j) x 64(i) x K=1024 tile (no empty blocks, uniform load balance).
// Block: 256 thr = 4 waves; wave w handles j in [j0+64w, j0+64w+64).
// __launch_bounds__(256,4): verified r13 — compiler re-balances (48 arch VGPR + AGPR accs),
// occupancy 40%, best measured config for this latency-bound stream.
__global__ __launch_bounds__(256, 4) void simtopk_f16(const _Float16* __restrict__ xf,
                                                      int* __restrict__ cand_idx,
                                                      float* __restrict__ cand_val) {
    __shared__ float mv[64 * 4 * M_];            // 12KB merge buffers
    __shared__ int   mi[64 * 4 * M_];            // 12KB

    const int bid = blockIdx.x;
    const int b   = bid / NTILE_B;
    const int u   = bid - b * NTILE_B;
    // unflatten u -> (t, s): groups q=t>>2 have 4 tiles x (q+1) segments; C(q)=2q(q+1)
    int q = 0;
#pragma unroll
    for (int qq = 1; qq < 16; ++qq) if (u >= 2 * qq * (qq + 1)) q = qq;
    const int rr = u - 2 * q * (q + 1);
    const int dt = rr / (q + 1);
    const int s  = rr - dt * (q + 1);
    const int t  = (q << 2) + dt;
    const int i0 = t << 6;
    const int j0 = s << 8;

    const int tid  = threadIdx.x;
    const int wid  = tid >> 6;
    const int lane = tid & 63;
    const int l31  = lane & 31;
    const int lhi  = lane >> 5;

    const f16x8* Fb = reinterpret_cast<const f16x8*>(xf) + (size_t)b * 128 * T_;

    const int myc = i0 + (lhi << 5) + l31;       // the single i column this lane owns
    const int jbw = j0 + (wid << 6);

    float tv[M_]; int tix[M_];
#pragma unroll
    for (int k = 0; k < M_; ++k) { tv[k] = -INFINITY; tix[k] = -1; }

    f32x16 acc00, acc01, acc10, acc11;
#pragma unroll
    for (int r = 0; r < 16; ++r) { acc00[r] = 0.f; acc01[r] = 0.f; acc10[r] = 0.f; acc11[r] = 0.f; }

#pragma unroll 4
    for (int kh = 0; kh < 16; ++kh) {            // K chunks of 64 elements = 8 packs
#pragma unroll
        for (int ks = 0; ks < 4; ++ks) {
            const int p = (kh << 3) + (ks << 1) + lhi;
            const f16x8* Fp = Fb + (size_t)p * T_;
            const f16x8 aj0 = Fp[jbw + l31];
            const f16x8 aj1 = Fp[jbw + 32 + l31];
            const f16x8 bi0 = Fp[i0 + l31];
            const f16x8 bi1 = Fp[i0 + 32 + l31];
            acc00 = __builtin_amdgcn_mfma_f32_32x32x16_f16(aj0, bi0, acc00, 0, 0, 0);
            acc01 = __builtin_amdgcn_mfma_f32_32x32x16_f16(aj0, bi1, acc01, 0, 0, 0);
            acc10 = __builtin_amdgcn_mfma_f32_32x32x16_f16(aj1, bi0, acc10, 0, 0, 0);
            acc11 = __builtin_amdgcn_mfma_f32_32x32x16_f16(aj1, bi1, acc11, 0, 0, 0);
        }
    }

    // consolidate to one column per lane and scan 64 j-values in registers
#pragma unroll
    for (int r = 0; r < 16; ++r) {
        const float swA = __shfl_xor(acc00[r], 32);
        const float swB = __shfl_xor(acc01[r], 32);
        const float swC = __shfl_xor(acc10[r], 32);
        const float swD = __shfl_xor(acc11[r], 32);
        const int rbase = (r & 3) + ((r >> 2) << 3);
        const int rown  = jbw + rbase + (lhi << 2);        // own half rows
        const int rotn  = jbw + rbase + ((1 - lhi) << 2);  // partner half rows
        const float va = lhi ? acc01[r] : acc00[r];        // (rown,      myc)
        const float vb = lhi ? swB      : swA;             // (rotn,      myc)
        const float vc = lhi ? acc11[r] : acc10[r];        // (rown + 32, myc)
        const float vd = lhi ? swD      : swC;             // (rotn + 32, myc)
        if (rown <= myc      && va > tv[0]) ins12(tv, tix, va, rown);
        if (rotn <= myc      && vb > tv[0]) ins12(tv, tix, vb, rotn);
        if (rown + 32 <= myc && vc > tv[0]) ins12(tv, tix, vc, rown + 32);
        if (rotn + 32 <= myc && vd > tv[0]) ins12(tv, tix, vd, rotn + 32);
    }

    // merge 4 wave-lists per column via LDS
    const int coll = (lhi << 5) + l31;
#pragma unroll
    for (int k = 0; k < M_; ++k) {
        mv[(coll * 4 + wid) * M_ + k] = tv[k];
        mi[(coll * 4 + wid) * M_ + k] = tix[k];
    }
    __syncthreads();
    if (tid < 64) {
        float gv[M_]; int gx[M_];
#pragma unroll
        for (int k = 0; k < M_; ++k) { gv[k] = -INFINITY; gx[k] = -1; }
        for (int ls = 0; ls < 4; ++ls) {
            const int base = (tid * 4 + ls) * M_;
            for (int k = M_ - 1; k >= 0; --k) {      // stored ascending; walk descending
                const float v = mv[base + k];
                if (!(v > gv[0])) break;
                const int nj = mi[base + k];
                if (nj >= 0) ins12(gv, gx, v, nj);
            }
        }
        const size_t cb = ((size_t)(b * T_ + i0 + tid) * NSEG_F16 + s) * M_;
#pragma unroll
        for (int k = 0; k < M_; ++k) {
            cand_val[cb + k] = gv[M_ - 1 - k];
            cand_idx[cb + k] = gx[M_ - 1 - k];
        }
    }
}

// ---------------- Kernel 2b: fp32 fallback (used only if workspace too small) ----------------
__global__ __launch_bounds__(256) void simtopk_fp32(const float* __restrict__ x,
                                                    const float* __restrict__ rn32,
                                                    int* __restrict__ cand_idx,
                                                    float* __restrict__ cand_val,
                                                    int SEGJT, int NSEGMAX) {
    __shared__ __align__(16) float smem2[DC * 36 + DC * 132];
    float (*At)[36]  = reinterpret_cast<float(*)[36]>(smem2);
    float (*Bt)[132] = reinterpret_cast<float(*)[132]>(smem2 + DC * 36);
    float (*Cs)[132] = reinterpret_cast<float(*)[132]>(smem2);

    const int bid = blockIdx.x;
    const int s   = bid % NSEGMAX;
    const int bt  = bid / NSEGMAX;
    const int t   = bt & 127;
    const int b   = bt >> 7;
    const int njt = (t >> 2) + 1;
    const int jt0 = s * SEGJT;
    if (jt0 >= njt) return;
    const int jt1 = min(jt0 + SEGJT, njt);
    const int i0  = t * BI;

    const int tid = threadIdx.x;
    const int tx  = tid & 31;
    const int ty  = tid >> 5;
    const float* xb = x + (size_t)b * T_ * D_;
    const float* rb = rn32 + b * T_;

    const int ai  = tid >> 3;
    const int adq = (tid & 7) << 2;

    float tv[M_]; int tix[M_];
#pragma unroll
    for (int k = 0; k < M_; ++k) { tv[k] = -INFINITY; tix[k] = -1; }

    for (int jt = jt0; jt < jt1; ++jt) {
        const int j0 = jt << 7;
        float acc[4][4];
#pragma unroll
        for (int ii = 0; ii < 4; ++ii)
#pragma unroll
            for (int jj = 0; jj < 4; ++jj) acc[ii][jj] = 0.f;

        for (int dc = 0; dc < D_; dc += DC) {
            __syncthreads();
            {
                const float rn = rb[i0 + ai];
                float4 v = *reinterpret_cast<const float4*>(&xb[(size_t)(i0 + ai) * D_ + dc + adq]);
                At[adq + 0][ai] = v.x * rn;
                At[adq + 1][ai] = v.y * rn;
                At[adq + 2][ai] = v.z * rn;
                At[adq + 3][ai] = v.w * rn;
            }
#pragma unroll
            for (int l = 0; l < 4; ++l) {
                const int li = tid + (l << 8);
                const int j  = li >> 3;
                const int dq = (li & 7) << 2;
                const float rn = rb[j0 + j];
                float4 v = *reinterpret_cast<const float4*>(&xb[(size_t)(j0 + j) * D_ + dc + dq]);
                Bt[dq + 0][j] = v.x * rn;
                Bt[dq + 1][j] = v.y * rn;
                Bt[dq + 2][j] = v.z * rn;
                Bt[dq + 3][j] = v.w * rn;
            }
            __syncthreads();
#pragma unroll 8
            for (int d = 0; d < DC; ++d) {
                float4 a  = *reinterpret_cast<const float4*>(&At[d][ty << 2]);
                float4 bv = *reinterpret_cast<const float4*>(&Bt[d][tx << 2]);
                float av[4] = {a.x, a.y, a.z, a.w};
                float bw[4] = {bv.x, bv.y, bv.z, bv.w};
#pragma unroll
                for (int ii = 0; ii < 4; ++ii)
#pragma unroll
                    for (int jj = 0; jj < 4; ++jj)
                        acc[ii][jj] = fmaf(av[ii], bw[jj], acc[ii][jj]);
            }
        }
        __syncthreads();
#pragma unroll
        for (int ii = 0; ii < 4; ++ii) {
            *reinterpret_cast<float4*>(&Cs[(ty << 2) + ii][tx << 2]) =
                make_float4(acc[ii][0], acc[ii][1], acc[ii][2], acc[ii][3]);
        }
        __syncthreads();
        if (tid < BI) {
            const int gi   = i0 + tid;
            const int jmax = gi - j0;
            const int cend = jmax < BJ - 1 ? jmax : BJ - 1;
            for (int c = 0; c <= cend; ++c) {
                const float v = Cs[tid][c];
                if (v > tv[0]) ins12(tv, tix, v, j0 + c);
            }
        }
    }
    if (tid < BI) {
        const size_t base = ((size_t)(b * T_ + i0 + tid) * NSEGMAX + s) * M_;
#pragma unroll
        for (int k = 0; k < M_; ++k) {
            cand_idx[base + k] = tix[M_ - 1 - k];
            cand_val[base + k] = tv[M_ - 1 - k];
        }
    }
}

// ---------------- Kernel 3a: wave-per-row rank-merge + fp64 refine -> sel[] ----------------
__global__ __launch_bounds__(256) void select_kernel(const float* __restrict__ x,
                                                     const double* __restrict__ rn64,
                                                     const int* __restrict__ cand_idx,
                                                     const float* __restrict__ cand_val,
                                                     int* __restrict__ sel,
                                                     int SEGJT, int NSEGMAX, int SHIFT) {
    const int tid  = threadIdx.x;
    const int wid  = tid >> 6;
    const int lane = tid & 63;
    const int row  = (blockIdx.x << 2) + wid;
    const int b    = row >> 12;
    const int i    = row & (T_ - 1);
    const int njt  = (i >> SHIFT) + 1;
    const int nseg = (njt + SEGJT - 1) / SEGJT;
    const int ncand = nseg * M_;              // <= 192

    __shared__ unsigned long long keys[4][192];
    __shared__ float v12[4][12];
    __shared__ int   i12[4][12];

    if (lane < 12) { v12[wid][lane] = -INFINITY; i12[wid][lane] = -1; }

    const size_t cb = (size_t)row * NSEGMAX * M_;
    float cv[3]; int cj[3]; unsigned long long kk[3];
#pragma unroll
    for (int q = 0; q < 3; ++q) {
        const int c = lane + (q << 6);
        if (c < ncand) { cv[q] = cand_val[cb + c]; cj[q] = cand_idx[cb + c]; }
        else           { cv[q] = -INFINITY;        cj[q] = -1; }
        unsigned u = __float_as_uint(cv[q]);
        unsigned so = (u & 0x80000000u) ? ~u : (u | 0x80000000u);
        kk[q] = (cj[q] >= 0)
              ? ((((unsigned long long)so) << 32) | (unsigned long long)(0xFFFFFFFFu - (unsigned)cj[q]))
              : 0ull;
        keys[wid][lane + (q << 6)] = kk[q];
    }
    int nv = 0;
#pragma unroll
    for (int q = 0; q < 3; ++q) nv += __popcll(__ballot(cj[q] >= 0));
    __syncthreads();

    int rk0 = 0, rk1 = 0, rk2 = 0;
#pragma unroll 4
    for (int c = 0; c < ncand; ++c) {
        const unsigned long long kc = keys[wid][c];
        rk0 += (kc > kk[0]);
        rk1 += (kc > kk[1]);
        rk2 += (kc > kk[2]);
    }
    if (cj[0] >= 0 && rk0 < 12) { v12[wid][rk0] = cv[0]; i12[wid][rk0] = cj[0]; }
    if (cj[1] >= 0 && rk1 < 12) { v12[wid][rk1] = cv[1]; i12[wid][rk1] = cj[1]; }
    if (cj[2] >= 0 && rk2 < 12) { v12[wid][rk2] = cv[2]; i12[wid][rk2] = cj[2]; }
    __syncthreads();

    const float v8 = v12[wid][7];
    const float v9 = v12[wid][8];
    const bool refine = (nv > K_) && (v8 - v9 < 2e-4f);   // wave-uniform

    int outj = -1;
    int cnt;
    if (refine) {
        const float* xi = x + (size_t)row * D_;
        float4 xa[4];
#pragma unroll
        for (int q = 0; q < 4; ++q)
            xa[q] = *reinterpret_cast<const float4*>(xi + (lane << 4) + (q << 2));
        double sim[12]; int jj[12];
#pragma unroll
        for (int c = 0; c < 12; ++c) {
            const int j = i12[wid][c];
            jj[c] = j;
            double s = 0.0;
            if (j >= 0) {
                const float* xj = x + ((size_t)(b << 12) + j) * D_;
#pragma unroll
                for (int q = 0; q < 4; ++q) {
                    const float4 xc = *reinterpret_cast<const float4*>(xj + (lane << 4) + (q << 2));
                    s += (double)xa[q].x * xc.x + (double)xa[q].y * xc.y +
                         (double)xa[q].z * xc.z + (double)xa[q].w * xc.w;
                }
            }
            sim[c] = s;
        }
#pragma unroll
        for (int c = 0; c < 12; ++c) {
#pragma unroll
            for (int o = 1; o < 64; o <<= 1) sim[c] += __shfl_xor(sim[c], o);
        }
        const double rni = rn64[row];
#pragma unroll
        for (int c = 0; c < 12; ++c)
            sim[c] = (jj[c] >= 0) ? sim[c] * rni * rn64[(b << 12) + jj[c]] : -1e300;
        unsigned msel = 0;
#pragma unroll
        for (int c = 0; c < 12; ++c) {
            int r = 0;
#pragma unroll
            for (int d = 0; d < 12; ++d) {
                if (d == c) continue;
                r += (sim[d] > sim[c]) || (sim[d] == sim[c] && jj[d] < jj[c]);
            }
            if (jj[c] >= 0 && r < 8) msel |= (1u << c);
        }
        cnt = __popc(msel); if (cnt < 1) cnt = 1;
        if (lane < 8) {
            int seen = 0;
#pragma unroll
            for (int c = 0; c < 12; ++c) {
                if (msel & (1u << c)) { if (seen == lane) outj = jj[c]; ++seen; }
            }
        }
    } else {
        cnt = nv < K_ ? nv : K_; if (cnt < 1) cnt = 1;
        if (lane < 8) outj = i12[wid][lane];
    }
    if (lane < 8) sel[(row << 4) + lane] = outj;
    if (lane == 8) sel[(row << 4) + 8] = cnt;
}

// ---------------- Kernel 3b: streaming gather + gate epilogue ----------------
__global__ __launch_bounds__(256) void gather_kernel(const float* __restrict__ x,
                                                     const int* __restrict__ sel,
                                                     const float* __restrict__ gain,
                                                     const float* __restrict__ bias,
                                                     const float* __restrict__ lmix,
                                                     const float* __restrict__ lscale,
                                                     float* __restrict__ out) {
    const int row = blockIdx.x;
    const int b   = row >> 12;
    const int tid = threadIdx.x;
    const int sb  = row << 4;

    int js[8];
#pragma unroll
    for (int k = 0; k < 8; ++k) js[k] = sel[sb + k];
    const int cnt = sel[sb + 8];

    const float4 xiv = reinterpret_cast<const float4*>(x + (size_t)row * D_)[tid];
    float mx = 0.f, my = 0.f, mz = 0.f, mw = 0.f;
#pragma unroll
    for (int k = 0; k < 8; ++k) {
        const int j = js[k];
        if (j >= 0) {
            const float4 xc = reinterpret_cast<const float4*>(
                x + ((size_t)(b << 12) + j) * D_)[tid];
            mx += xc.x; my += xc.y; mz += xc.z; mw += xc.w;
        }
    }
    const float inv = 1.0f / (float)cnt;
    const float lm = lmix[0], ls = lscale[0];
    const float mix = 1.0f / (1.0f + expf(-lm));
    const float sc  = (fmaxf(ls, 0.f) + log1pf(expf(-fabsf(ls)))) + 0.01f;
    const float4 g  = reinterpret_cast<const float4*>(gain)[tid];
    const float4 bb = reinterpret_cast<const float4*>(bias)[tid];

    float4 o4;
    {
        float m, bl, y;
        m = mx * inv; bl = mix * xiv.x + (1.f - mix) * m; y = bl * g.x + bb.x;
        o4.x = 0.5f * y * (1.f + erff(y * 0.70710678118654752f)) * sc;
        m = my * inv; bl = mix * xiv.y + (1.f - mix) * m; y = bl * g.y + bb.y;
        o4.y = 0.5f * y * (1.f + erff(y * 0.70710678118654752f)) * sc;
        m = mz * inv; bl = mix * xiv.z + (1.f - mix) * m; y = bl * g.z + bb.z;
        o4.z = 0.5f * y * (1.f + erff(y * 0.70710678118654752f)) * sc;
        m = mw * inv; bl = mix * xiv.w + (1.f - mix) * m; y = bl * g.w + bb.w;
        o4.w = 0.5f * y * (1.f + erff(y * 0.70710678118654752f)) * sc;
    }
    reinterpret_cast<float4*>(out + (size_t)row * D_)[tid] = o4;
}

// ---------------- launch ----------------
extern "C" void kernel_launch(void* const* d_in, const int* in_sizes, int n_in,
                              void* d_out, int out_size, void* d_ws, size_t ws_size,
                              hipStream_t stream) {
    const float* x      = (const float*)d_in[0];
    const float* gain   = (const float*)d_in[1];
    const float* bias   = (const float*)d_in[2];
    const float* lmix   = (const float*)d_in[3];
    const float* lscale = (const float*)d_in[4];
    float* out = (float*)d_out;

    char* ws = (char*)d_ws;
    float*  rn32 = (float*)ws;                        // 64 KB
    double* rn64 = (double*)(ws + 65536);             // 128 KB
    int*    selb = (int*)(ws + 196608);               // B*T*16 ints = 1 MB
    const size_t base2 = 196608 + (size_t)B_ * T_ * 16 * 4;
    const size_t HF = (size_t)B_ * T_ * D_ * 2;       // 32 MB fp16 pack-major array
    _Float16* xf = (_Float16*)(ws + base2);
    const size_t base_cand = base2 + HF;

    auto candBytes = [](int nseg) { return (size_t)B_ * T_ * nseg * M_ * 8; };

    const bool use_f16 = (ws_size >= base_cand + candBytes(NSEG_F16));

    if (use_f16) {
        int*   cidx = (int*)(ws + base_cand);
        float* cval = (float*)(ws + base_cand + candBytes(NSEG_F16) / 2);
        norm_transpose_kernel<<<dim3(B_ * T_ / 64), dim3(256), 0, stream>>>(x, rn32, rn64, xf);
        simtopk_f16<<<dim3(B_ * NTILE_B), dim3(256), 0, stream>>>(xf, cidx, cval);
        select_kernel<<<dim3(B_ * T_ / 4), dim3(256), 0, stream>>>(
            x, rn64, cidx, cval, selb, 1, NSEG_F16, 8);
    } else {
        int SEG2, NSEG2;
        if (ws_size >= base2 + candBytes(9)) { SEG2 = 4;  NSEG2 = 9; }
        else                                 { SEG2 = 33; NSEG2 = 1; }
        int*   cidx = (int*)(ws + base2);
        float* cval = (float*)(ws + base2 + candBytes(NSEG2) / 2);
        norm_kernel<<<dim3(B_ * T_), dim3(256), 0, stream>>>(x, rn32, rn64);
        simtopk_fp32<<<dim3(B_ * 128 * NSEG2), dim3(256), 0, stream>>>(x, rn32, cidx, cval, SEG2, NSEG2);
        select_kernel<<<dim3(B_ * T_ / 4), dim3(256), 0, stream>>>(
            x, rn64, cidx, cval, selb, SEG2, NSEG2, 7);
    }
    gather_kernel<<<dim3(B_ * T_), dim3(256), 0, stream>>>(
        x, selb, gain, bias, lmix, lscale, out);
}

// Round 17
// 299.721 us; speedup vs baseline: 1.1024x; 1.0028x over previous
//
#include <hip/hip_runtime.h>
#include <math.h>

#define B_ 4
#define T_ 4096
#define D_ 1024
#define K_ 8
#define M_ 12          // candidates kept per row/segment (refined to top-K)

// f16 MFMA path: SEGJT=1 (one 256-wide j-tile per block), NSEG=16 segment slots
#define NSEG_F16 16
#define NTILE_B  544   // sum over t=0..63 of njt(t) = (t>>2)+1

// fallback fp32-path tile params
#define BI 32
#define BJ 128
#define DC 32

typedef __attribute__((ext_vector_type(8))) _Float16 f16x8;
typedef __attribute__((ext_vector_type(16))) float f32x16;

// branch-free sorted insert into ascending top-12 (tv[0]=min). Static indices.
__device__ __forceinline__ void ins12(float (&tv)[M_], int (&tix)[M_], float v, int nj) {
#pragma unroll
    for (int k = 0; k < M_; ++k) {
        const float nxt = (k < M_ - 1) ? tv[k + 1] : INFINITY;
        const int   nxi = (k < M_ - 1) ? tix[k + 1] : -1;
        const bool  up  = v > nxt;
        const bool  mid = v > tv[k];
        tv[k]  = up ? nxt : (mid ? v  : tv[k]);
        tix[k] = up ? nxi : (mid ? nj : tix[k]);
    }
}

// ---------------- Kernel 1 (fused): row norms (fp64 truth) + normalize + pack-major transpose ----------------
__global__ __launch_bounds__(256) void norm_transpose_kernel(const float* __restrict__ x,
                                                             float* __restrict__ rn32,
                                                             double* __restrict__ rn64,
                                                             _Float16* __restrict__ xf) {
    const int blk = blockIdx.x;                  // 0 .. B*T/64-1
    const int b   = blk >> 6;                    // 64 blocks per batch
    const int i0b = (blk & 63) << 6;
    const int tid = threadIdx.x;
    const int r   = tid >> 2;                    // 0..63 row within tile
    const int q   = tid & 3;                     // quarter
    const int row = i0b + r;
    const float* src = x + ((size_t)(b << 12) + row) * D_ + (q << 8);   // 256 floats

    double ss = 0.0;
#pragma unroll 8
    for (int g = 0; g < 64; ++g) {
        const float4 v = reinterpret_cast<const float4*>(src)[g];
        ss += (double)v.x * v.x + (double)v.y * v.y +
              (double)v.z * v.z + (double)v.w * v.w;
    }
    // quad reduce (lanes 4r..4r+3 are in the same wave)
    ss += __shfl_xor(ss, 1);
    ss += __shfl_xor(ss, 2);
    const double rn = 1.0 / (sqrt(ss) + 1e-8);
    if (q == 0) {
        rn64[(b << 12) + row] = rn;
        rn32[(b << 12) + row] = (float)rn;
    }
    const float rnf = (float)rn;
    f16x8* dst = reinterpret_cast<f16x8*>(xf) + (size_t)b * 128 * T_;
#pragma unroll
    for (int g = 0; g < 32; ++g) {
        const int p = (q << 5) + g;              // packs 32q .. 32q+31
        const float4 a = reinterpret_cast<const float4*>(src)[g << 1];
        const float4 c = reinterpret_cast<const float4*>(src)[(g << 1) + 1];
        f16x8 h;
        h[0] = (_Float16)(a.x * rnf); h[1] = (_Float16)(a.y * rnf);
        h[2] = (_Float16)(a.z * rnf); h[3] = (_Float16)(a.w * rnf);
        h[4] = (_Float16)(c.x * rnf); h[5] = (_Float16)(c.y * rnf);
        h[6] = (_Float16)(c.z * rnf); h[7] = (_Float16)(c.w * rnf);
        dst[(size_t)p * T_ + row] = h;
    }
}

// ---------------- Kernel 1-fallback: row norms only (fp32 path) ----------------
__global__ __launch_bounds__(256) void norm_kernel(const float* __restrict__ x,
                                                   float* __restrict__ rn32,
                                                   double* __restrict__ rn64) {
    const int row = blockIdx.x;
    const int tid = threadIdx.x;
    const float4 v = reinterpret_cast<const float4*>(x + (size_t)row * D_)[tid];
    double ss = (double)v.x * v.x + (double)v.y * v.y +
                (double)v.z * v.z + (double)v.w * v.w;
    for (int o = 32; o > 0; o >>= 1) ss += __shfl_down(ss, o);
    __shared__ double ws[4];
    if ((tid & 63) == 0) ws[tid >> 6] = ss;
    __syncthreads();
    if (tid == 0) {
        double s = ws[0] + ws[1] + ws[2] + ws[3];
        double rn = 1.0 / (sqrt(s) + 1e-8);
        rn64[row] = rn;
        rn32[row] = (float)rn;
    }
}

// ---------------- Kernel 2a: fp16 MFMA similarity — uniform-work streaming tiles, s-major ----------------
// Grid: B * 544 blocks; per batch tiles ordered s-MAJOR: offset O(s)=s*(66-2s); for s
// fixed, t = 4s + (u - O(s)), t in [4s, 63]. Consecutive blocks share the same 512KB
// j-panel -> round-robin dispatch makes it L2-resident on every XCD (multicast reuse).
// Block: 256 thr = 4 waves; wave w handles j in [j0+64w, j0+64w+64). Per-wave body and
// __launch_bounds__(256,4) identical to the verified r13/r16 config.
__global__ __launch_bounds__(256, 4) void simtopk_f16(const _Float16* __restrict__ xf,
                                                      int* __restrict__ cand_idx,
                                                      float* __restrict__ cand_val) {
    __shared__ float mv[64 * 4 * M_];            // 12KB merge buffers
    __shared__ int   mi[64 * 4 * M_];            // 12KB

    const int bid = blockIdx.x;
    const int b   = bid / NTILE_B;
    const int u   = bid - b * NTILE_B;
    // s-major unflatten: O(s) = s*(66-2s); t = 4s + (u - O(s))
    int s = 0;
#pragma unroll
    for (int ss = 1; ss < 16; ++ss) if (u >= ss * (66 - 2 * ss)) s = ss;
    const int t  = (s << 2) + (u - s * (66 - 2 * s));
    const int i0 = t << 6;
    const int j0 = s << 8;

    const int tid  = threadIdx.x;
    const int wid  = tid >> 6;
    const int lane = tid & 63;
    const int l31  = lane & 31;
    const int lhi  = lane >> 5;

    const f16x8* Fb = reinterpret_cast<const f16x8*>(xf) + (size_t)b * 128 * T_;

    const int myc = i0 + (lhi << 5) + l31;       // the single i column this lane owns
    const int jbw = j0 + (wid << 6);

    float tv[M_]; int tix[M_];
#pragma unroll
    for (int k = 0; k < M_; ++k) { tv[k] = -INFINITY; tix[k] = -1; }

    f32x16 acc00, acc01, acc10, acc11;
#pragma unroll
    for (int r = 0; r < 16; ++r) { acc00[r] = 0.f; acc01[r] = 0.f; acc10[r] = 0.f; acc11[r] = 0.f; }

#pragma unroll 4
    for (int kh = 0; kh < 16; ++kh) {            // K chunks of 64 elements = 8 packs
#pragma unroll
        for (int ks = 0; ks < 4; ++ks) {
            const int p = (kh << 3) + (ks << 1) + lhi;
            const f16x8* Fp = Fb + (size_t)p * T_;
            const f16x8 aj0 = Fp[jbw + l31];
            const f16x8 aj1 = Fp[jbw + 32 + l31];
            const f16x8 bi0 = Fp[i0 + l31];
            const f16x8 bi1 = Fp[i0 + 32 + l31];
            acc00 = __builtin_amdgcn_mfma_f32_32x32x16_f16(aj0, bi0, acc00, 0, 0, 0);
            acc01 = __builtin_amdgcn_mfma_f32_32x32x16_f16(aj0, bi1, acc01, 0, 0, 0);
            acc10 = __builtin_amdgcn_mfma_f32_32x32x16_f16(aj1, bi0, acc10, 0, 0, 0);
            acc11 = __builtin_amdgcn_mfma_f32_32x32x16_f16(aj1, bi1, acc11, 0, 0, 0);
        }
    }

    // consolidate to one column per lane and scan 64 j-values in registers
#pragma unroll
    for (int r = 0; r < 16; ++r) {
        const float swA = __shfl_xor(acc00[r], 32);
        const float swB = __shfl_xor(acc01[r], 32);
        const float swC = __shfl_xor(acc10[r], 32);
        const float swD = __shfl_xor(acc11[r], 32);
        const int rbase = (r & 3) + ((r >> 2) << 3);
        const int rown  = jbw + rbase + (lhi << 2);        // own half rows
        const int rotn  = jbw + rbase + ((1 - lhi) << 2);  // partner half rows
        const float va = lhi ? acc01[r] : acc00[r];        // (rown,      myc)
        const float vb = lhi ? swB      : swA;             // (rotn,      myc)
        const float vc = lhi ? acc11[r] : acc10[r];        // (rown + 32, myc)
        const float vd = lhi ? swD      : swC;             // (rotn + 32, myc)
        if (rown <= myc      && va > tv[0]) ins12(tv, tix, va, rown);
        if (rotn <= myc      && vb > tv[0]) ins12(tv, tix, vb, rotn);
        if (rown + 32 <= myc && vc > tv[0]) ins12(tv, tix, vc, rown + 32);
        if (rotn + 32 <= myc && vd > tv[0]) ins12(tv, tix, vd, rotn + 32);
    }

    // merge 4 wave-lists per column via LDS
    const int coll = (lhi << 5) + l31;
#pragma unroll
    for (int k = 0; k < M_; ++k) {
        mv[(coll * 4 + wid) * M_ + k] = tv[k];
        mi[(coll * 4 + wid) * M_ + k] = tix[k];
    }
    __syncthreads();
    if (tid < 64) {
        float gv[M_]; int gx[M_];
#pragma unroll
        for (int k = 0; k < M_; ++k) { gv[k] = -INFINITY; gx[k] = -1; }
        for (int ls = 0; ls < 4; ++ls) {
            const int base = (tid * 4 + ls) * M_;
            for (int k = M_ - 1; k >= 0; --k) {      // stored ascending; walk descending
                const float v = mv[base + k];
                if (!(v > gv[0])) break;
                const int nj = mi[base + k];
                if (nj >= 0) ins12(gv, gx, v, nj);
            }
        }
        const size_t cb = ((size_t)(b * T_ + i0 + tid) * NSEG_F16 + s) * M_;
#pragma unroll
        for (int k = 0; k < M_; ++k) {
            cand_val[cb + k] = gv[M_ - 1 - k];
            cand_idx[cb + k] = gx[M_ - 1 - k];
        }
    }
}

// ---------------- Kernel 2b: fp32 fallback (used only if workspace too small) ----------------
__global__ __launch_bounds__(256) void simtopk_fp32(const float* __restrict__ x,
                                                    const float* __restrict__ rn32,
                                                    int* __restrict__ cand_idx,
                                                    float* __restrict__ cand_val,
                                                    int SEGJT, int NSEGMAX) {
    __shared__ __align__(16) float smem2[DC * 36 + DC * 132];
    float (*At)[36]  = reinterpret_cast<float(*)[36]>(smem2);
    float (*Bt)[132] = reinterpret_cast<float(*)[132]>(smem2 + DC * 36);
    float (*Cs)[132] = reinterpret_cast<float(*)[132]>(smem2);

    const int bid = blockIdx.x;
    const int s   = bid % NSEGMAX;
    const int bt  = bid / NSEGMAX;
    const int t   = bt & 127;
    const int b   = bt >> 7;
    const int njt = (t >> 2) + 1;
    const int jt0 = s * SEGJT;
    if (jt0 >= njt) return;
    const int jt1 = min(jt0 + SEGJT, njt);
    const int i0  = t * BI;

    const int tid = threadIdx.x;
    const int tx  = tid & 31;
    const int ty  = tid >> 5;
    const float* xb = x + (size_t)b * T_ * D_;
    const float* rb = rn32 + b * T_;

    const int ai  = tid >> 3;
    const int adq = (tid & 7) << 2;

    float tv[M_]; int tix[M_];
#pragma unroll
    for (int k = 0; k < M_; ++k) { tv[k] = -INFINITY; tix[k] = -1; }

    for (int jt = jt0; jt < jt1; ++jt) {
        const int j0 = jt << 7;
        float acc[4][4];
#pragma unroll
        for (int ii = 0; ii < 4; ++ii)
#pragma unroll
            for (int jj = 0; jj < 4; ++jj) acc[ii][jj] = 0.f;

        for (int dc = 0; dc < D_; dc += DC) {
            __syncthreads();
            {
                const float rn = rb[i0 + ai];
                float4 v = *reinterpret_cast<const float4*>(&xb[(size_t)(i0 + ai) * D_ + dc + adq]);
                At[adq + 0][ai] = v.x * rn;
                At[adq + 1][ai] = v.y * rn;
                At[adq + 2][ai] = v.z * rn;
                At[adq + 3][ai] = v.w * rn;
            }
#pragma unroll
            for (int l = 0; l < 4; ++l) {
                const int li = tid + (l << 8);
                const int j  = li >> 3;
                const int dq = (li & 7) << 2;
                const float rn = rb[j0 + j];
                float4 v = *reinterpret_cast<const float4*>(&xb[(size_t)(j0 + j) * D_ + dc + dq]);
                Bt[dq + 0][j] = v.x * rn;
                Bt[dq + 1][j] = v.y * rn;
                Bt[dq + 2][j] = v.z * rn;
                Bt[dq + 3][j] = v.w * rn;
            }
            __syncthreads();
#pragma unroll 8
            for (int d = 0; d < DC; ++d) {
                float4 a  = *reinterpret_cast<const float4*>(&At[d][ty << 2]);
                float4 bv = *reinterpret_cast<const float4*>(&Bt[d][tx << 2]);
                float av[4] = {a.x, a.y, a.z, a.w};
                float bw[4] = {bv.x, bv.y, bv.z, bv.w};
#pragma unroll
                for (int ii = 0; ii < 4; ++ii)
#pragma unroll
                    for (int jj = 0; jj < 4; ++jj)
                        acc[ii][jj] = fmaf(av[ii], bw[jj], acc[ii][jj]);
            }
        }
        __syncthreads();
#pragma unroll
        for (int ii = 0; ii < 4; ++ii) {
            *reinterpret_cast<float4*>(&Cs[(ty << 2) + ii][tx << 2]) =
                make_float4(acc[ii][0], acc[ii][1], acc[ii][2], acc[ii][3]);
        }
        __syncthreads();
        if (tid < BI) {
            const int gi   = i0 + tid;
            const int jmax = gi - j0;
            const int cend = jmax < BJ - 1 ? jmax : BJ - 1;
            for (int c = 0; c <= cend; ++c) {
                const float v = Cs[tid][c];
                if (v > tv[0]) ins12(tv, tix, v, j0 + c);
            }
        }
    }
    if (tid < BI) {
        const size_t base = ((size_t)(b * T_ + i0 + tid) * NSEGMAX + s) * M_;
#pragma unroll
        for (int k = 0; k < M_; ++k) {
            cand_idx[base + k] = tix[M_ - 1 - k];
            cand_val[base + k] = tv[M_ - 1 - k];
        }
    }
}

// ---------------- Kernel 3a: wave-per-row rank-merge + fp64 refine -> sel[] ----------------
__global__ __launch_bounds__(256) void select_kernel(const float* __restrict__ x,
                                                     const double* __restrict__ rn64,
                                                     const int* __restrict__ cand_idx,
                                                     const float* __restrict__ cand_val,
                                                     int* __restrict__ sel,
                                                     int SEGJT, int NSEGMAX, int SHIFT) {
    const int tid  = threadIdx.x;
    const int wid  = tid >> 6;
    const int lane = tid & 63;
    const int row  = (blockIdx.x << 2) + wid;
    const int b    = row >> 12;
    const int i    = row & (T_ - 1);
    const int njt  = (i >> SHIFT) + 1;
    const int nseg = (njt + SEGJT - 1) / SEGJT;
    const int ncand = nseg * M_;              // <= 192

    __shared__ unsigned long long keys[4][192];
    __shared__ float v12[4][12];
    __shared__ int   i12[4][12];

    if (lane < 12) { v12[wid][lane] = -INFINITY; i12[wid][lane] = -1; }

    const size_t cb = (size_t)row * NSEGMAX * M_;
    float cv[3]; int cj[3]; unsigned long long kk[3];
#pragma unroll
    for (int q = 0; q < 3; ++q) {
        const int c = lane + (q << 6);
        if (c < ncand) { cv[q] = cand_val[cb + c]; cj[q] = cand_idx[cb + c]; }
        else           { cv[q] = -INFINITY;        cj[q] = -1; }
        unsigned u = __float_as_uint(cv[q]);
        unsigned so = (u & 0x80000000u) ? ~u : (u | 0x80000000u);
        kk[q] = (cj[q] >= 0)
              ? ((((unsigned long long)so) << 32) | (unsigned long long)(0xFFFFFFFFu - (unsigned)cj[q]))
              : 0ull;
        keys[wid][lane + (q << 6)] = kk[q];
    }
    int nv = 0;
#pragma unroll
    for (int q = 0; q < 3; ++q) nv += __popcll(__ballot(cj[q] >= 0));
    __syncthreads();

    int rk0 = 0, rk1 = 0, rk2 = 0;
#pragma unroll 4
    for (int c = 0; c < ncand; ++c) {
        const unsigned long long kc = keys[wid][c];
        rk0 += (kc > kk[0]);
        rk1 += (kc > kk[1]);
        rk2 += (kc > kk[2]);
    }
    if (cj[0] >= 0 && rk0 < 12) { v12[wid][rk0] = cv[0]; i12[wid][rk0] = cj[0]; }
    if (cj[1] >= 0 && rk1 < 12) { v12[wid][rk1] = cv[1]; i12[wid][rk1] = cj[1]; }
    if (cj[2] >= 0 && rk2 < 12) { v12[wid][rk2] = cv[2]; i12[wid][rk2] = cj[2]; }
    __syncthreads();

    const float v8 = v12[wid][7];
    const float v9 = v12[wid][8];
    const bool refine = (nv > K_) && (v8 - v9 < 2e-4f);   // wave-uniform

    int outj = -1;
    int cnt;
    if (refine) {
        const float* xi = x + (size_t)row * D_;
        float4 xa[4];
#pragma unroll
        for (int q = 0; q < 4; ++q)
            xa[q] = *reinterpret_cast<const float4*>(xi + (lane << 4) + (q << 2));
        double sim[12]; int jj[12];
#pragma unroll
        for (int c = 0; c < 12; ++c) {
            const int j = i12[wid][c];
            jj[c] = j;
            double s = 0.0;
            if (j >= 0) {
                const float* xj = x + ((size_t)(b << 12) + j) * D_;
#pragma unroll
                for (int q = 0; q < 4; ++q) {
                    const float4 xc = *reinterpret_cast<const float4*>(xj + (lane << 4) + (q << 2));
                    s += (double)xa[q].x * xc.x + (double)xa[q].y * xc.y +
                         (double)xa[q].z * xc.z + (double)xa[q].w * xc.w;
                }
            }
            sim[c] = s;
        }
#pragma unroll
        for (int c = 0; c < 12; ++c) {
#pragma unroll
            for (int o = 1; o < 64; o <<= 1) sim[c] += __shfl_xor(sim[c], o);
        }
        const double rni = rn64[row];
#pragma unroll
        for (int c = 0; c < 12; ++c)
            sim[c] = (jj[c] >= 0) ? sim[c] * rni * rn64[(b << 12) + jj[c]] : -1e300;
        unsigned msel = 0;
#pragma unroll
        for (int c = 0; c < 12; ++c) {
            int r = 0;
#pragma unroll
            for (int d = 0; d < 12; ++d) {
                if (d == c) continue;
                r += (sim[d] > sim[c]) || (sim[d] == sim[c] && jj[d] < jj[c]);
            }
            if (jj[c] >= 0 && r < 8) msel |= (1u << c);
        }
        cnt = __popc(msel); if (cnt < 1) cnt = 1;
        if (lane < 8) {
            int seen = 0;
#pragma unroll
            for (int c = 0; c < 12; ++c) {
                if (msel & (1u << c)) { if (seen == lane) outj = jj[c]; ++seen; }
            }
        }
    } else {
        cnt = nv < K_ ? nv : K_; if (cnt < 1) cnt = 1;
        if (lane < 8) outj = i12[wid][lane];
    }
    if (lane < 8) sel[(row << 4) + lane] = outj;
    if (lane == 8) sel[(row << 4) + 8] = cnt;
}

// ---------------- Kernel 3b: streaming gather + gate epilogue ----------------
__global__ __launch_bounds__(256) void gather_kernel(const float* __restrict__ x,
                                                     const int* __restrict__ sel,
                                                     const float* __restrict__ gain,
                                                     const float* __restrict__ bias,
                                                     const float* __restrict__ lmix,
                                                     const float* __restrict__ lscale,
                                                     float* __restrict__ out) {
    const int row = blockIdx.x;
    const int b   = row >> 12;
    const int tid = threadIdx.x;
    const int sb  = row << 4;

    int js[8];
#pragma unroll
    for (int k = 0; k < 8; ++k) js[k] = sel[sb + k];
    const int cnt = sel[sb + 8];

    const float4 xiv = reinterpret_cast<const float4*>(x + (size_t)row * D_)[tid];
    float mx = 0.f, my = 0.f, mz = 0.f, mw = 0.f;
#pragma unroll
    for (int k = 0; k < 8; ++k) {
        const int j = js[k];
        if (j >= 0) {
            const float4 xc = reinterpret_cast<const float4*>(
                x + ((size_t)(b << 12) + j) * D_)[tid];
            mx += xc.x; my += xc.y; mz += xc.z; mw += xc.w;
        }
    }
    const float inv = 1.0f / (float)cnt;
    const float lm = lmix[0], ls = lscale[0];
    const float mix = 1.0f / (1.0f + expf(-lm));
    const float sc  = (fmaxf(ls, 0.f) + log1pf(expf(-fabsf(ls)))) + 0.01f;
    const float4 g  = reinterpret_cast<const float4*>(gain)[tid];
    const float4 bb = reinterpret_cast<const float4*>(bias)[tid];

    float4 o4;
    {
        float m, bl, y;
        m = mx * inv; bl = mix * xiv.x + (1.f - mix) * m; y = bl * g.x + bb.x;
        o4.x = 0.5f * y * (1.f + erff(y * 0.70710678118654752f)) * sc;
        m = my * inv; bl = mix * xiv.y + (1.f - mix) * m; y = bl * g.y + bb.y;
        o4.y = 0.5f * y * (1.f + erff(y * 0.70710678118654752f)) * sc;
        m = mz * inv; bl = mix * xiv.z + (1.f - mix) * m; y = bl * g.z + bb.z;
        o4.z = 0.5f * y * (1.f + erff(y * 0.70710678118654752f)) * sc;
        m = mw * inv; bl = mix * xiv.w + (1.f - mix) * m; y = bl * g.w + bb.w;
        o4.w = 0.5f * y * (1.f + erff(y * 0.70710678118654752f)) * sc;
    }
    reinterpret_cast<float4*>(out + (size_t)row * D_)[tid] = o4;
}

// ---------------- launch ----------------
extern "C" void kernel_launch(void* const* d_in, const int* in_sizes, int n_in,
                              void* d_out, int out_size, void* d_ws, size_t ws_size,
                              hipStream_t stream) {
    const float* x      = (const float*)d_in[0];
    const float* gain   = (const float*)d_in[1];
    const float* bias   = (const float*)d_in[2];
    const float* lmix   = (const float*)d_in[3];
    const float* lscale = (const float*)d_in[4];
    float* out = (float*)d_out;

    char* ws = (char*)d_ws;
    float*  rn32 = (float*)ws;                        // 64 KB
    double* rn64 = (double*)(ws + 65536);             // 128 KB
    int*    selb = (int*)(ws + 196608);               // B*T*16 ints = 1 MB
    const size_t base2 = 196608 + (size_t)B_ * T_ * 16 * 4;
    const size_t HF = (size_t)B_ * T_ * D_ * 2;       // 32 MB fp16 pack-major array
    _Float16* xf = (_Float16*)(ws + base2);
    const size_t base_cand = base2 + HF;

    auto candBytes = [](int nseg) { return (size_t)B_ * T_ * nseg * M_ * 8; };

    const bool use_f16 = (ws_size >= base_cand + candBytes(NSEG_F16));

    if (use_f16) {
        int*   cidx = (int*)(ws + base_cand);
        float* cval = (float*)(ws + base_cand + candBytes(NSEG_F16) / 2);
        norm_transpose_kernel<<<dim3(B_ * T_ / 64), dim3(256), 0, stream>>>(x, rn32, rn64, xf);
        simtopk_f16<<<dim3(B_ * NTILE_B), dim3(256), 0, stream>>>(xf, cidx, cval);
        select_kernel<<<dim3(B_ * T_ / 4), dim3(256), 0, stream>>>(
            x, rn64, cidx, cval, selb, 1, NSEG_F16, 8);
    } else {
        int SEG2, NSEG2;
        if (ws_size >= base2 + candBytes(9)) { SEG2 = 4;  NSEG2 = 9; }
        else                                 { SEG2 = 33; NSEG2 = 1; }
        int*   cidx = (int*)(ws + base2);
        float* cval = (float*)(ws + base2 + candBytes(NSEG2) / 2);
        norm_kernel<<<dim3(B_ * T_), dim3(256), 0, stream>>>(x, rn32, rn64);
        simtopk_fp32<<<dim3(B_ * 128 * NSEG2), dim3(256), 0, stream>>>(x, rn32, cidx, cval, SEG2, NSEG2);
        select_kernel<<<dim3(B_ * T_ / 4), dim3(256), 0, stream>>>(
            x, rn64, cidx, cval, selb, SEG2, NSEG2, 7);
    }
    gather_kernel<<<dim3(B_ * T_), dim3(256), 0, stream>>>(
        x, selb, gain, bias, lmix, lscale, out);
}